// Round 2
// baseline (471.076 us; speedup 1.0000x reference)
//
#include <hip/hip_runtime.h>

using u16 = unsigned short;
using u32 = unsigned int;
typedef __attribute__((ext_vector_type(8))) short bf16x8;
typedef __attribute__((ext_vector_type(4))) float f32x4;

// ---------- posit(8,1) round-to-nearest, bit-exact vs the numpy reference ----------
// posit(8,1): fbits = clip(6 - regime_len, 0, 23) <= 4  -> all outputs exact in bf16.
__device__ __forceinline__ float posit_q(float x) {
    float a = __builtin_fabsf(x);
    u32 u = __float_as_uint(a);
    int logx = (int)(u >> 23) - 127;              // floor(log2(a)) for normal a
    logx = logx < -60 ? -60 : (logx > 60 ? 60 : logx);  // out-of-range -> clamped to minpos/maxpos anyway
    float frac = __uint_as_float((u & 0x007fffffu) | 0x3f800000u);  // [1,2)
    int k = logx >> 1;                            // floor(logx/2), es=1
    int rl = (k >= 0) ? (k + 2) : (1 - k);        // regime length
    int fb = 6 - rl; fb = fb < 0 ? 0 : fb;        // fraction bits, <=4
    float step = (float)(1 << fb);
    // rintf = round-half-even, matches jnp.round; all scalings are exact powers of 2
    float q = rintf(frac * step) * __uint_as_float((u32)(127 + logx - fb) << 23);
    q = fminf(fmaxf(q, 0x1p-12f), 0x1p12f);       // clip(minpos, maxpos), nbits=8 es=1
    return (a > 0.0f) ? copysignf(q, x) : 0.0f;
}

__device__ __forceinline__ float b2f(u16 v) { return __uint_as_float((u32)v << 16); }
__device__ __forceinline__ u16 f2b(float f) { return (u16)(__float_as_uint(f) >> 16); }  // exact for posit values

// ---------- kernel 1: quantize weights ----------
// w2frag layout: [wave(4)][kc(9)][lane(64)][e(8)] so conv2 B-frags are coalesced 16B loads.
// B[k][n], k = kc*32 + (lane>>4)*8 + e (ci), n = wave*16 + (lane&15); kc = kh*3+kw.
__global__ __launch_bounds__(256) void prep_kernel(
    const float* __restrict__ w1, const float* __restrict__ w2,
    const float* __restrict__ fw1, const float* __restrict__ fw2,
    float* __restrict__ w1q, u16* __restrict__ w2frag,
    u16* __restrict__ fc1wq, float* __restrict__ fc2wq) {
    int i = blockIdx.x * 256 + threadIdx.x;
    if (i < 288)  w1q[i]   = posit_q(w1[i]);
    if (i < 1280) fc2wq[i] = posit_q(fw2[i]);
    if (i < 18432) {
        int e = i & 7, lane = (i >> 3) & 63, c9 = i >> 9;
        int kc = c9 % 9, w = c9 / 9;
        int n = w * 16 + (lane & 15);
        int ci = ((lane >> 4) << 3) + e;
        w2frag[i] = f2b(posit_q(w2[n * 288 + ci * 9 + kc]));  // w2 flat [n][ci][kh][kw]
    }
    if (i < 1179648) fc1wq[i] = f2b(posit_q(fw1[i]));         // [n=128][k=9216], k-contiguous (NT)
}

// ---------- kernel 2: quantize input ----------
__global__ __launch_bounds__(256) void xq_kernel(const float* __restrict__ x, u16* __restrict__ xq) {
    int i = blockIdx.x * 256 + threadIdx.x;   // grid exactly covers 4096*784
    xq[i] = f2b(posit_q(x[i]));
}

// ---------- kernel 3: conv1 + bias + relu + pq, output layout [img][y*26+x][oc] bf16 ----------
__global__ __launch_bounds__(256) void conv1_kernel(const u16* __restrict__ xq,
    const float* __restrict__ w1q, const float* __restrict__ b1, u16* __restrict__ h1q) {
    __shared__ float sx[784];
    __shared__ float sw[288];
    __shared__ float sb[32];
    int img = blockIdx.x, tid = threadIdx.x;
    for (int i = tid; i < 784; i += 256) sx[i] = b2f(xq[(size_t)img * 784 + i]);
    for (int i = tid; i < 288; i += 256) sw[i] = w1q[i];   // FIX: was `if (tid < 288)` with 256 threads
    if (tid < 32)  sb[tid] = b1[tid];
    __syncthreads();
    for (int p = tid; p < 676; p += 256) {
        int y = p / 26, xx = p - y * 26;
        float in9[9];
#pragma unroll
        for (int r = 0; r < 3; ++r)
#pragma unroll
            for (int c = 0; c < 3; ++c) in9[r * 3 + c] = sx[(y + r) * 28 + xx + c];
        u32 words[16];
#pragma unroll
        for (int oc = 0; oc < 32; oc += 2) {
            float a0 = sb[oc], a1 = sb[oc + 1];
#pragma unroll
            for (int j = 0; j < 9; ++j) {
                a0 = fmaf(sw[oc * 9 + j], in9[j], a0);
                a1 = fmaf(sw[oc * 9 + 9 + j], in9[j], a1);
            }
            u32 lo = f2b(posit_q(fmaxf(a0, 0.0f)));
            u32 hi = f2b(posit_q(fmaxf(a1, 0.0f)));
            words[oc >> 1] = lo | (hi << 16);
        }
        uint4* dst = (uint4*)(h1q + ((size_t)img * 676 + p) * 32);
        dst[0] = make_uint4(words[0], words[1], words[2], words[3]);
        dst[1] = make_uint4(words[4], words[5], words[6], words[7]);
        dst[2] = make_uint4(words[8], words[9], words[10], words[11]);
        dst[3] = make_uint4(words[12], words[13], words[14], words[15]);
    }
}

// ---------- kernel 4: conv2 (implicit GEMM, MFMA 16x16x32 bf16) + bias + relu + 2x2 maxpool + pq ----------
// Per image: M=576 (m permuted so one lane's 4 C-rows = one 2x2 pool window), N=64, K=288.
// C/D layout (m89-verified): col = lane&15 (n), row = (lane>>4)*4 + reg (m).
__global__ __launch_bounds__(256, 2) void conv2_kernel(const u16* __restrict__ h1q,
    const u16* __restrict__ w2frag, const float* __restrict__ b2, u16* __restrict__ pooled) {
    __shared__ __align__(16) u16 sIn[26 * 26 * 32];   // 43264 B, [y*26+x][ci]
    __shared__ __align__(16) u16 sPool[64 * 152];     // 19456 B, [c][pidx], stride 152 (16B-aligned rows)
    int img = blockIdx.x, tid = threadIdx.x;
    int wave = tid >> 6, lane = tid & 63;
    int col = lane & 15, quad = lane >> 4;

    {   // stage input image (contiguous copy: conv1 wrote [y][x][ci])
        const uint4* src = (const uint4*)(h1q + (size_t)img * 21632);
        uint4* dst = (uint4*)sIn;
        for (int i = tid; i < 2704; i += 256) dst[i] = src[i];
    }
    bf16x8 bfrag[9];
    {   // B-frags: coalesced 16B loads from frag-ready layout
        const bf16x8* wsrc = (const bf16x8*)w2frag + (wave * 576 + lane);
#pragma unroll
        for (int kc = 0; kc < 9; ++kc) bfrag[kc] = wsrc[kc * 64];
    }
    float bias = b2[wave * 16 + col];
    __syncthreads();

    for (int mt = 0; mt < 36; ++mt) {
        // A-row for this lane: m -> (oh,ow) via pool-window permutation
        int m = mt * 16 + col;
        int pp = m >> 2, wi = m & 3;
        int py = pp / 12, px = pp - py * 12;
        int oh = 2 * py + (wi >> 1), ow = 2 * px + (wi & 1);
        const u16* ap = &sIn[(oh * 26 + ow) * 32 + (quad << 3)];
        f32x4 acc = {0.f, 0.f, 0.f, 0.f};
#pragma unroll
        for (int kc = 0; kc < 9; ++kc) {
            int kh = kc / 3, kw = kc % 3;
            bf16x8 af = *(const bf16x8*)(ap + (kh * 26 + kw) * 32);  // ds_read_b128
            acc = __builtin_amdgcn_mfma_f32_16x16x32_bf16(af, bfrag[kc], acc, 0, 0, 0);
        }
        // lane holds rows quad*4+{0..3} = one full 2x2 pool window -> pool in-register
        float v0 = fmaxf(acc[0] + bias, 0.f);
        float v1 = fmaxf(acc[1] + bias, 0.f);
        float v2 = fmaxf(acc[2] + bias, 0.f);
        float v3 = fmaxf(acc[3] + bias, 0.f);
        float mx = fmaxf(fmaxf(v0, v1), fmaxf(v2, v3));
        sPool[(wave * 16 + col) * 152 + mt * 4 + quad] = f2b(posit_q(mx));
    }
    __syncthreads();
    // writeout pooled image, c-major (matches fc1 K layout), coalesced 16B chunks
    for (int u = tid; u < 1152; u += 256) {
        int c = u / 18, g = u - c * 18;
        uint4 v = *(const uint4*)&sPool[c * 152 + g * 8];
        *(uint4*)(pooled + (size_t)img * 9216 + c * 144 + g * 8) = v;
    }
}

// ---------- kernel 5: fc1 (MFMA NT-GEMM M=4096,N=128,K=9216) + bias + relu + pq, fused fc2 ----------
__global__ __launch_bounds__(256) void fc_kernel(const u16* __restrict__ pooled,
    const u16* __restrict__ fc1wq, const float* __restrict__ fc1b,
    const float* __restrict__ fc2wq, const float* __restrict__ fc2b,
    float* __restrict__ out) {
    __shared__ __align__(16) u16 sFc1[16 * 128];
    __shared__ float sW2[1280];
    __shared__ float sB2[10];
    int blk = blockIdx.x, tid = threadIdx.x;
    int wave = tid >> 6, lane = tid & 63;
    int row = lane & 15, quad = lane >> 4;
    int m0 = blk * 16;
    for (int i = tid; i < 1280; i += 256) sW2[i] = fc2wq[i];
    if (tid < 10) sB2[tid] = fc2b[tid];

    const bf16x8* ap  = (const bf16x8*)(pooled + (size_t)(m0 + row) * 9216) + quad;
    const bf16x8* bp0 = (const bf16x8*)(fc1wq + (size_t)(wave * 32 + row) * 9216) + quad;
    const bf16x8* bp1 = (const bf16x8*)(fc1wq + (size_t)(wave * 32 + 16 + row) * 9216) + quad;
    f32x4 acc0 = {0.f, 0.f, 0.f, 0.f}, acc1 = {0.f, 0.f, 0.f, 0.f};
#pragma unroll 4
    for (int kk = 0; kk < 288; ++kk) {
        bf16x8 a  = ap[kk * 4];
        bf16x8 b0 = bp0[kk * 4];
        bf16x8 b1 = bp1[kk * 4];
        acc0 = __builtin_amdgcn_mfma_f32_16x16x32_bf16(a, b0, acc0, 0, 0, 0);
        acc1 = __builtin_amdgcn_mfma_f32_16x16x32_bf16(a, b1, acc1, 0, 0, 0);
    }
    float bb0 = fc1b[wave * 32 + row];
    float bb1 = fc1b[wave * 32 + 16 + row];
#pragma unroll
    for (int r = 0; r < 4; ++r) {
        int ml = quad * 4 + r;
        sFc1[ml * 128 + wave * 32 + row]      = f2b(posit_q(fmaxf(acc0[r] + bb0, 0.f)));
        sFc1[ml * 128 + wave * 32 + 16 + row] = f2b(posit_q(fmaxf(acc1[r] + bb1, 0.f)));
    }
    __syncthreads();
    if (tid < 160) {
        int il = tid / 10, oc = tid - il * 10;
        float s = sB2[oc];
        const u16* hp = &sFc1[il * 128];
        const float* wp = &sW2[oc * 128];
#pragma unroll
        for (int k = 0; k < 128; ++k) s = fmaf(b2f(hp[k]), wp[k], s);
        out[(size_t)(m0 + il) * 10 + oc] = s;
    }
}

extern "C" void kernel_launch(void* const* d_in, const int* in_sizes, int n_in,
                              void* d_out, int out_size, void* d_ws, size_t ws_size,
                              hipStream_t stream) {
    const float* x    = (const float*)d_in[0];
    const float* w1   = (const float*)d_in[1];
    const float* b1   = (const float*)d_in[2];
    const float* w2   = (const float*)d_in[3];
    const float* b2   = (const float*)d_in[4];
    const float* fw1  = (const float*)d_in[5];
    const float* fb1  = (const float*)d_in[6];
    const float* fw2  = (const float*)d_in[7];
    const float* fb2  = (const float*)d_in[8];
    float* out = (float*)d_out;

    char* ws = (char*)d_ws;
    float* w1q     = (float*)(ws + 0);           // 1152 B
    float* fc2wq   = (float*)(ws + 1280);        // 5120 B
    u16*   w2frag  = (u16*)(ws + 6400);          // 36864 B
    u16*   fc1wq   = (u16*)(ws + 43520);         // 2359296 B
    u16*   xq      = (u16*)(ws + 2402816);       // 6422528 B
    u16*   h1q     = (u16*)(ws + 8825344);       // 177209344 B, [img][y*26+x][oc] bf16
    u16*   pooled  = (u16*)(ws + 186034688);     // 75497472 B,  [img][c*144 + y*12 + x] bf16
    // total 261532160 B

    prep_kernel<<<4608, 256, 0, stream>>>(w1, w2, fw1, fw2, w1q, w2frag, fc1wq, fc2wq);
    xq_kernel<<<12544, 256, 0, stream>>>(x, xq);
    conv1_kernel<<<4096, 256, 0, stream>>>(xq, w1q, b1, h1q);
    conv2_kernel<<<4096, 256, 0, stream>>>(h1q, w2frag, b2, pooled);
    fc_kernel<<<256, 256, 0, stream>>>(pooled, fc1wq, fb1, fc2wq, fb2, out);
}

// Round 3
// 337.453 us; speedup vs baseline: 1.3960x; 1.3960x over previous
//
#include <hip/hip_runtime.h>

using u16 = unsigned short;
using u32 = unsigned int;
typedef __attribute__((ext_vector_type(8))) short bf16x8;
typedef __attribute__((ext_vector_type(4))) float f32x4;

// ---------- posit(8,1) round-to-nearest; all outputs exact in bf16 ----------
__device__ __forceinline__ float posit_q(float x) {
    float a = __builtin_fabsf(x);
    u32 u = __float_as_uint(a);
    int logx = (int)(u >> 23) - 127;
    logx = logx < -60 ? -60 : (logx > 60 ? 60 : logx);
    float frac = __uint_as_float((u & 0x007fffffu) | 0x3f800000u);  // [1,2)
    int k = logx >> 1;                            // floor(logx/2), es=1
    int rl = (k >= 0) ? (k + 2) : (1 - k);        // regime length
    int fb = 6 - rl; fb = fb < 0 ? 0 : fb;        // fraction bits, <=4
    float step = (float)(1 << fb);
    float q = rintf(frac * step) * __uint_as_float((u32)(127 + logx - fb) << 23);
    q = fminf(fmaxf(q, 0x1p-12f), 0x1p12f);
    return (a > 0.0f) ? copysignf(q, x) : 0.0f;
}

__device__ __forceinline__ float b2f(u16 v) { return __uint_as_float((u32)v << 16); }
__device__ __forceinline__ u16 f2b(float f) { return (u16)(__float_as_uint(f) >> 16); }

// ---------- kernel 1: quantize weights ----------
// w2frag layout: [nt(4)][kc(9)][lane(64)][e(8)]; B[k][n], k=kc*32+(lane>>4)*8+e (ci), n=nt*16+(lane&15).
__global__ __launch_bounds__(256) void prep_kernel(
    const float* __restrict__ w1, const float* __restrict__ w2,
    const float* __restrict__ fw1, const float* __restrict__ fw2,
    float* __restrict__ w1q, u16* __restrict__ w2frag,
    u16* __restrict__ fc1wq, float* __restrict__ fc2wq) {
    int i = blockIdx.x * 256 + threadIdx.x;
    if (i < 288)  w1q[i]   = posit_q(w1[i]);
    if (i < 1280) fc2wq[i] = posit_q(fw2[i]);
    if (i < 18432) {
        int e = i & 7, lane = (i >> 3) & 63, c9 = i >> 9;
        int kc = c9 % 9, nt = c9 / 9;
        int n = nt * 16 + (lane & 15);
        int ci = ((lane >> 4) << 3) + e;
        w2frag[i] = f2b(posit_q(w2[n * 288 + ci * 9 + kc]));  // w2 flat [n][ci][kh][kw]
    }
    if (i < 1179648) fc1wq[i] = f2b(posit_q(fw1[i]));         // [n=128][k=9216]
}

// ---------- kernel 2: fused pq(x) + conv1 + relu + pq + conv2(MFMA) + bias + relu + pool + pq ----------
// Per block = one image. conv2: M=576 (pool-permuted), N=64, K=288; waves split M (9 mt each),
// each wave computes all 4 n-tiles with B held in 144 VGPRs -> 1 ds_read_b128 feeds 4 MFMA.
__global__ __launch_bounds__(256, 2) void conv_fused_kernel(
    const float* __restrict__ x, const float* __restrict__ w1q, const float* __restrict__ b1,
    const u16* __restrict__ w2frag, const float* __restrict__ b2, u16* __restrict__ pooled) {
    __shared__ __align__(16) u16 sX[784];            // 1568 B, pq(x) bf16
    __shared__ __align__(16) u16 sH1[676 * 32];      // 43264 B, [y*26+x][ci]
    __shared__ __align__(16) u16 sPool[64 * 152];    // 19456 B, [c][pidx], elem-stride 152 (304 B, 16B-aligned)
    int img = blockIdx.x, tid = threadIdx.x;
    int wave = tid >> 6, lane = tid & 63;
    int col = lane & 15, quad = lane >> 4;

    // phase 0: load + pq input image
    for (int i = tid; i < 784; i += 256) sX[i] = f2b(posit_q(x[(size_t)img * 784 + i]));

    // conv1 weights for this thread's oc pair (registers; 16-lane broadcast via L1)
    int ocp = tid & 15;
    float wreg[18];
#pragma unroll
    for (int j = 0; j < 18; ++j) wreg[j] = w1q[ocp * 18 + j];
    float bias0 = b1[ocp * 2], bias1 = b1[ocp * 2 + 1];

    // conv2 B-frags: 36 x b128 into registers (w2frag is 36 KB, L2/L3-resident)
    bf16x8 barr[4][9];
#pragma unroll
    for (int nt = 0; nt < 4; ++nt)
#pragma unroll
        for (int kc = 0; kc < 9; ++kc)
            barr[nt][kc] = *(const bf16x8*)(w2frag + ((nt * 9 + kc) * 64 + lane) * 8);
    float cb[4];
#pragma unroll
    for (int nt = 0; nt < 4; ++nt) cb[nt] = b2[nt * 16 + col];

    __syncthreads();

    // phase 1: conv1 (+bias+relu+pq) -> sH1. thread = (pixel-group, oc-pair).
    int pgrp = tid >> 4;
    for (int it = 0; it < 43; ++it) {
        int p = it * 16 + pgrp;
        if (p < 676) {
            int y = p / 26, xx = p - y * 26;
            const u16* px = &sX[y * 28 + xx];
            float in9[9];
#pragma unroll
            for (int r = 0; r < 3; ++r)
#pragma unroll
                for (int c = 0; c < 3; ++c) in9[r * 3 + c] = b2f(px[r * 28 + c]);
            float a0 = bias0, a1 = bias1;
#pragma unroll
            for (int j = 0; j < 9; ++j) {
                a0 = fmaf(wreg[j], in9[j], a0);
                a1 = fmaf(wreg[9 + j], in9[j], a1);
            }
            u32 w = (u32)f2b(posit_q(fmaxf(a0, 0.f))) | ((u32)f2b(posit_q(fmaxf(a1, 0.f))) << 16);
            *(u32*)&sH1[p * 32 + ocp * 2] = w;   // banks: 2-way (free)
        }
    }
    __syncthreads();

    // phase 2: conv2 MFMA + bias + relu + in-register 2x2 pool + pq
    for (int t = 0; t < 9; ++t) {
        int mt = wave * 9 + t;
        int m = mt * 16 + col;                  // pool-permuted m for the A operand (row = lane&15)
        int pp = m >> 2, wi = m & 3;
        int py = pp / 12, px_ = pp - py * 12;
        int oh = 2 * py + (wi >> 1), ow = 2 * px_ + (wi & 1);
        const u16* ap = &sH1[(oh * 26 + ow) * 32 + quad * 8];
        f32x4 acc[4];
#pragma unroll
        for (int nt = 0; nt < 4; ++nt) acc[nt] = f32x4{0.f, 0.f, 0.f, 0.f};
#pragma unroll
        for (int kc = 0; kc < 9; ++kc) {
            int kh = kc / 3, kw = kc - kh * 3;
            bf16x8 af = *(const bf16x8*)(ap + (kh * 26 + kw) * 32);  // 1 read : 4 MFMA
#pragma unroll
            for (int nt = 0; nt < 4; ++nt)
                acc[nt] = __builtin_amdgcn_mfma_f32_16x16x32_bf16(af, barr[nt][kc], acc[nt], 0, 0, 0);
        }
        // C/D: row = quad*4+reg, col = lane&15 -> lane's 4 regs = one full 2x2 pool window
#pragma unroll
        for (int nt = 0; nt < 4; ++nt) {
            float v0 = fmaxf(acc[nt][0] + cb[nt], 0.f);
            float v1 = fmaxf(acc[nt][1] + cb[nt], 0.f);
            float v2 = fmaxf(acc[nt][2] + cb[nt], 0.f);
            float v3 = fmaxf(acc[nt][3] + cb[nt], 0.f);
            float mx = fmaxf(fmaxf(v0, v1), fmaxf(v2, v3));
            sPool[(nt * 16 + col) * 152 + mt * 4 + quad] = f2b(posit_q(mx));
        }
    }
    __syncthreads();

    // phase 3: coalesced writeout, c-major (fc1 K layout)
    for (int u = tid; u < 1152; u += 256) {
        int c = u / 18, g = u - c * 18;
        uint4 v = *(const uint4*)&sPool[c * 152 + g * 8];
        *(uint4*)(pooled + (size_t)img * 9216 + c * 144 + g * 8) = v;
    }
}

// ---------- kernel 3: fc1 (M=4096,N=128,K=9216) + bias + relu + pq, fused fc2 ----------
// 512 threads = 8 waves; wave w owns K-slice w*1152..+1151, computes all 8 n-tiles (9 loads in flight),
// partials tree-reduced in LDS. 256 blocks -> 2 waves/SIMD.
__global__ __launch_bounds__(512, 2) void fc_kernel(const u16* __restrict__ pooled,
    const u16* __restrict__ fc1wq, const float* __restrict__ fc1b,
    const float* __restrict__ fc2wq, const float* __restrict__ fc2b,
    float* __restrict__ out) {
    __shared__ __align__(16) float sAcc[4][16 * 132];   // padded stride 132: 2-way banks
    __shared__ __align__(16) u16 sFc1[16 * 128];
    __shared__ float sW2[1280];
    __shared__ float sB2[16];
    int blk = blockIdx.x, tid = threadIdx.x;
    int wave = tid >> 6, lane = tid & 63;
    int row = lane & 15, quad = lane >> 4;
    int m0 = blk * 16;
    for (int i = tid; i < 1280; i += 512) sW2[i] = fc2wq[i];
    if (tid < 10) sB2[tid] = fc2b[tid];

    const bf16x8* ap = (const bf16x8*)(pooled + (size_t)(m0 + row) * 9216 + wave * 1152) + quad;
    const bf16x8* bp[8];
#pragma unroll
    for (int nt = 0; nt < 8; ++nt)
        bp[nt] = (const bf16x8*)(fc1wq + (size_t)(nt * 16 + row) * 9216 + wave * 1152) + quad;
    f32x4 acc[8];
#pragma unroll
    for (int nt = 0; nt < 8; ++nt) acc[nt] = f32x4{0.f, 0.f, 0.f, 0.f};
#pragma unroll 4
    for (int ks = 0; ks < 36; ++ks) {
        bf16x8 a = ap[ks * 4];
#pragma unroll
        for (int nt = 0; nt < 8; ++nt)
            acc[nt] = __builtin_amdgcn_mfma_f32_16x16x32_bf16(a, bp[nt][ks * 4], acc[nt], 0, 0, 0);
    }
    // reduce 8 partials -> 4 -> 1
    if (wave < 4) {
#pragma unroll
        for (int nt = 0; nt < 8; ++nt)
#pragma unroll
            for (int r = 0; r < 4; ++r)
                sAcc[wave][(quad * 4 + r) * 132 + nt * 16 + row] = acc[nt][r];
    }
    __syncthreads();
    if (wave >= 4) {
#pragma unroll
        for (int nt = 0; nt < 8; ++nt)
#pragma unroll
            for (int r = 0; r < 4; ++r)
                sAcc[wave - 4][(quad * 4 + r) * 132 + nt * 16 + row] += acc[nt][r];
    }
    __syncthreads();
    for (int e = tid; e < 2048; e += 512) {
        int ml = e >> 7, n = e & 127;
        int o = ml * 132 + n;
        float s = sAcc[0][o] + sAcc[1][o] + sAcc[2][o] + sAcc[3][o];
        sFc1[e] = f2b(posit_q(fmaxf(s + fc1b[n], 0.f)));
    }
    __syncthreads();
    if (tid < 160) {
        int il = tid / 10, oc = tid - il * 10;
        float s = sB2[oc];
        const u16* hp = &sFc1[il * 128];
        const float* wp = &sW2[oc * 128];
#pragma unroll
        for (int k = 0; k < 128; ++k) s = fmaf(b2f(hp[k]), wp[k], s);
        out[(size_t)(m0 + il) * 10 + oc] = s;
    }
}

extern "C" void kernel_launch(void* const* d_in, const int* in_sizes, int n_in,
                              void* d_out, int out_size, void* d_ws, size_t ws_size,
                              hipStream_t stream) {
    const float* x    = (const float*)d_in[0];
    const float* w1   = (const float*)d_in[1];
    const float* b1   = (const float*)d_in[2];
    const float* w2   = (const float*)d_in[3];
    const float* b2   = (const float*)d_in[4];
    const float* fw1  = (const float*)d_in[5];
    const float* fb1  = (const float*)d_in[6];
    const float* fw2  = (const float*)d_in[7];
    const float* fb2  = (const float*)d_in[8];
    float* out = (float*)d_out;

    char* ws = (char*)d_ws;
    float* w1q     = (float*)(ws + 0);           // 1152 B
    float* fc2wq   = (float*)(ws + 1280);        // 5120 B
    u16*   w2frag  = (u16*)(ws + 6400);          // 36864 B
    u16*   fc1wq   = (u16*)(ws + 43520);         // 2359296 B
    u16*   pooled  = (u16*)(ws + 2402816);       // 75497472 B, [img][c*144 + y*12 + x] bf16
    // total ~78 MB

    prep_kernel<<<4608, 256, 0, stream>>>(w1, w2, fw1, fw2, w1q, w2frag, fc1wq, fc2wq);
    conv_fused_kernel<<<4096, 256, 0, stream>>>(x, w1q, b1, w2frag, b2, pooled);
    fc_kernel<<<256, 512, 0, stream>>>(pooled, fc1wq, fb1, fc2wq, fb2, out);
}

// Round 5
// 331.339 us; speedup vs baseline: 1.4217x; 1.0185x over previous
//
#include <hip/hip_runtime.h>

using u16 = unsigned short;
using u32 = unsigned int;
typedef __attribute__((ext_vector_type(8))) short bf16x8;
typedef __attribute__((ext_vector_type(4))) float f32x4;

// ---------- posit(8,1) round-to-nearest (float core, round-3 verified bit-exact) ----------
__device__ __forceinline__ float posit_q(float x) {
    float a = __builtin_fabsf(x);
    u32 u = __float_as_uint(a);
    int logx = (int)(u >> 23) - 127;
    logx = logx < -60 ? -60 : (logx > 60 ? 60 : logx);
    float frac = __uint_as_float((u & 0x007fffffu) | 0x3f800000u);  // [1,2)
    int k = logx >> 1;                            // floor(logx/2), es=1
    int rl = (k >= 0) ? (k + 2) : (1 - k);        // regime length
    int fb = 6 - rl; fb = fb < 0 ? 0 : fb;        // fraction bits, <=4
    float step = (float)(1 << fb);
    float q = rintf(frac * step) * __uint_as_float((u32)(127 + logx - fb) << 23);
    q = fminf(fmaxf(q, 0x1p-12f), 0x1p12f);
    return (a > 0.0f) ? copysignf(q, x) : 0.0f;
}

__device__ __forceinline__ float b2f(u16 v) { return __uint_as_float((u32)v << 16); }
__device__ __forceinline__ u16 f2b(float f) { return (u16)(__float_as_uint(f) >> 16); }  // exact for posit values

// ---------- kernel 1: quantize weights ----------
// w2frag layout: [nt(4)][kc(9)][lane(64)][e(8)]; B[k][n], k=kc*32+(lane>>4)*8+e (ci), n=nt*16+(lane&15).
__global__ __launch_bounds__(256) void prep_kernel(
    const float* __restrict__ w1, const float* __restrict__ w2,
    const float* __restrict__ fw1, const float* __restrict__ fw2,
    float* __restrict__ w1q, u16* __restrict__ w2frag,
    u16* __restrict__ fc1wq, float* __restrict__ fc2wq) {
    int i = blockIdx.x * 256 + threadIdx.x;
    if (i < 288)  w1q[i]   = posit_q(w1[i]);
    if (i < 1280) fc2wq[i] = posit_q(fw2[i]);
    if (i < 18432) {
        int e = i & 7, lane = (i >> 3) & 63, c9 = i >> 9;
        int kc = c9 % 9, nt = c9 / 9;
        int n = nt * 16 + (lane & 15);
        int ci = ((lane >> 4) << 3) + e;
        w2frag[i] = f2b(posit_q(w2[n * 288 + ci * 9 + kc]));  // w2 flat [n][ci][kh][kw]
    }
    if (i < 1179648) fc1wq[i] = f2b(posit_q(fw1[i]));         // [n=128][k=9216]
}

// ---------- kernel 2: fused pq(x) + conv1 + relu + pq + conv2(MFMA) + bias + relu + pool + pq ----------
// Per block = one image. conv2: M=576 (pool-permuted), N=64, K=288; waves split M (9 mt each),
// each wave computes all 4 n-tiles with B held in 144 VGPRs -> 1 ds_read_b128 feeds 4 MFMA.
// sH1 pixel stride 40 u16 (80 B, 16B-aligned).
#define H1S 40
__global__ __launch_bounds__(256, 2) void conv_fused_kernel(
    const float* __restrict__ x, const float* __restrict__ w1q, const float* __restrict__ b1,
    const u16* __restrict__ w2frag, const float* __restrict__ b2, u16* __restrict__ pooled) {
    __shared__ __align__(16) float sX[784];           // 3136 B
    __shared__ __align__(16) u16 sH1[676 * H1S];      // 54080 B
    __shared__ __align__(16) u16 sPool[64 * 152];     // 19456 B  (total 76672 B -> 2 blocks/CU)
    int img = blockIdx.x, tid = threadIdx.x;
    int wave = tid >> 6, lane = tid & 63;
    int col = lane & 15, quad = lane >> 4;

    // phase 0: load + pq input image (posit values are f32-exact)
    for (int i = tid; i < 784; i += 256) sX[i] = posit_q(x[(size_t)img * 784 + i]);

    // conv1 weights for this thread's oc pair (registers)
    int ocp = tid & 15;
    float wreg[18];
#pragma unroll
    for (int j = 0; j < 18; ++j) wreg[j] = w1q[ocp * 18 + j];
    float bias0 = b1[ocp * 2], bias1 = b1[ocp * 2 + 1];
    float cb[4];
#pragma unroll
    for (int nt = 0; nt < 4; ++nt) cb[nt] = b2[nt * 16 + col];

    __syncthreads();

    // phase 1: conv1 (+bias+relu+pq) -> sH1. thread = (pixel-group pgrp, oc-pair ocp). Explicit fmaf.
    int pgrp = tid >> 4;
    for (int it = 0; it < 43; ++it) {
        int p = it * 16 + pgrp;
        if (p < 676) {
            int y = p / 26, xx = p - y * 26;
            const float* px = &sX[y * 28 + xx];
            float in9[9];
#pragma unroll
            for (int r = 0; r < 3; ++r)
#pragma unroll
                for (int c = 0; c < 3; ++c) in9[r * 3 + c] = px[r * 28 + c];
            float a0 = bias0, a1 = bias1;
#pragma unroll
            for (int j = 0; j < 9; ++j) {
                a0 = fmaf(wreg[j], in9[j], a0);
                a1 = fmaf(wreg[9 + j], in9[j], a1);
            }
            u32 w = (u32)f2b(posit_q(fmaxf(a0, 0.f))) | ((u32)f2b(posit_q(fmaxf(a1, 0.f))) << 16);
            *(u32*)&sH1[p * H1S + ocp * 2] = w;
        }
    }

    // conv2 B-frags: loaded AFTER phase 1 so their live range is phase 2 only (no spill/remat)
    __syncthreads();
    bf16x8 barr[4][9];
#pragma unroll
    for (int nt = 0; nt < 4; ++nt)
#pragma unroll
        for (int kc = 0; kc < 9; ++kc)
            barr[nt][kc] = *(const bf16x8*)(w2frag + ((nt * 9 + kc) * 64 + lane) * 8);

    // phase 2: conv2 MFMA + pool(max) + bias + relu + pq
    for (int t = 0; t < 9; ++t) {
        int mt = wave * 9 + t;
        int m = mt * 16 + col;                  // pool-permuted m (A-row = lane&15)
        int pp = m >> 2, wi = m & 3;
        int py = pp / 12, px_ = pp - py * 12;
        int oh = 2 * py + (wi >> 1), ow = 2 * px_ + (wi & 1);
        const u16* ap = &sH1[(oh * 26 + ow) * H1S + quad * 8];
        f32x4 acc[4];
#pragma unroll
        for (int nt = 0; nt < 4; ++nt) acc[nt] = f32x4{0.f, 0.f, 0.f, 0.f};
#pragma unroll
        for (int kc = 0; kc < 9; ++kc) {
            int kh = kc / 3, kw = kc - kh * 3;
            bf16x8 af = *(const bf16x8*)(ap + (kh * 26 + kw) * H1S);  // 1 ds_read_b128 : 4 MFMA
#pragma unroll
            for (int nt = 0; nt < 4; ++nt)
                acc[nt] = __builtin_amdgcn_mfma_f32_16x16x32_bf16(af, barr[nt][kc], acc[nt], 0, 0, 0);
        }
        // C/D: row = quad*4+reg -> lane's 4 regs = one 2x2 pool window; max commutes exactly
        // with monotone +bias and relu, so pool first.
#pragma unroll
        for (int nt = 0; nt < 4; ++nt) {
            float mx = fmaxf(fmaxf(acc[nt][0], acc[nt][1]), fmaxf(acc[nt][2], acc[nt][3]));
            sPool[(nt * 16 + col) * 152 + mt * 4 + quad] = f2b(posit_q(fmaxf(mx + cb[nt], 0.f)));
        }
    }
    __syncthreads();

    // phase 3: coalesced writeout, c-major (fc1 K layout)
    for (int u = tid; u < 1152; u += 256) {
        int c = u / 18, g = u - c * 18;
        uint4 v = *(const uint4*)&sPool[c * 152 + g * 8];
        *(uint4*)(pooled + (size_t)img * 9216 + c * 144 + g * 8) = v;
    }
}

// ---------- kernel 3: fc1 (M=4096,N=128,K=9216) + bias + relu + pq, fused fc2 ----------
__global__ __launch_bounds__(512, 2) void fc_kernel(const u16* __restrict__ pooled,
    const u16* __restrict__ fc1wq, const float* __restrict__ fc1b,
    const float* __restrict__ fc2wq, const float* __restrict__ fc2b,
    float* __restrict__ out) {
    __shared__ __align__(16) float sAcc[4][16 * 132];
    __shared__ __align__(16) u16 sFc1[16 * 128];
    __shared__ float sW2[1280];
    __shared__ float sB2[16];
    int blk = blockIdx.x, tid = threadIdx.x;
    int wave = tid >> 6, lane = tid & 63;
    int row = lane & 15, quad = lane >> 4;
    int m0 = blk * 16;
    for (int i = tid; i < 1280; i += 512) sW2[i] = fc2wq[i];
    if (tid < 10) sB2[tid] = fc2b[tid];

    const bf16x8* ap = (const bf16x8*)(pooled + (size_t)(m0 + row) * 9216 + wave * 1152) + quad;
    const bf16x8* bp[8];
#pragma unroll
    for (int nt = 0; nt < 8; ++nt)
        bp[nt] = (const bf16x8*)(fc1wq + (size_t)(nt * 16 + row) * 9216 + wave * 1152) + quad;
    f32x4 acc[8];
#pragma unroll
    for (int nt = 0; nt < 8; ++nt) acc[nt] = f32x4{0.f, 0.f, 0.f, 0.f};
#pragma unroll 4
    for (int ks = 0; ks < 36; ++ks) {
        bf16x8 a = ap[ks * 4];
#pragma unroll
        for (int nt = 0; nt < 8; ++nt)
            acc[nt] = __builtin_amdgcn_mfma_f32_16x16x32_bf16(a, bp[nt][ks * 4], acc[nt], 0, 0, 0);
    }
    if (wave < 4) {
#pragma unroll
        for (int nt = 0; nt < 8; ++nt)
#pragma unroll
            for (int r = 0; r < 4; ++r)
                sAcc[wave][(quad * 4 + r) * 132 + nt * 16 + row] = acc[nt][r];
    }
    __syncthreads();
    if (wave >= 4) {
#pragma unroll
        for (int nt = 0; nt < 8; ++nt)
#pragma unroll
            for (int r = 0; r < 4; ++r)
                sAcc[wave - 4][(quad * 4 + r) * 132 + nt * 16 + row] += acc[nt][r];
    }
    __syncthreads();
    for (int e = tid; e < 2048; e += 512) {
        int ml = e >> 7, n = e & 127;
        int o = ml * 132 + n;
        float s = sAcc[0][o] + sAcc[1][o] + sAcc[2][o] + sAcc[3][o];
        sFc1[e] = f2b(posit_q(fmaxf(s + fc1b[n], 0.f)));
    }
    __syncthreads();
    if (tid < 160) {
        int il = tid / 10, oc = tid - il * 10;
        float s = sB2[oc];
        const u16* hp = &sFc1[il * 128];
        const float* wp = &sW2[oc * 128];
#pragma unroll
        for (int k = 0; k < 128; ++k) s = fmaf(b2f(hp[k]), wp[k], s);
        out[(size_t)(m0 + il) * 10 + oc] = s;
    }
}

extern "C" void kernel_launch(void* const* d_in, const int* in_sizes, int n_in,
                              void* d_out, int out_size, void* d_ws, size_t ws_size,
                              hipStream_t stream) {
    const float* x    = (const float*)d_in[0];
    const float* w1   = (const float*)d_in[1];
    const float* b1   = (const float*)d_in[2];
    const float* w2   = (const float*)d_in[3];
    const float* b2   = (const float*)d_in[4];
    const float* fw1  = (const float*)d_in[5];
    const float* fb1  = (const float*)d_in[6];
    const float* fw2  = (const float*)d_in[7];
    const float* fb2  = (const float*)d_in[8];
    float* out = (float*)d_out;

    char* ws = (char*)d_ws;
    float* w1q     = (float*)(ws + 0);           // 1152 B
    float* fc2wq   = (float*)(ws + 1280);        // 5120 B
    u16*   w2frag  = (u16*)(ws + 6400);          // 36864 B
    u16*   fc1wq   = (u16*)(ws + 43520);         // 2359296 B
    u16*   pooled  = (u16*)(ws + 2402816);       // 75497472 B, [img][c*144 + y*12 + x] bf16
    // total ~78 MB

    prep_kernel<<<4608, 256, 0, stream>>>(w1, w2, fw1, fw2, w1q, w2frag, fc1wq, fc2wq);
    conv_fused_kernel<<<4096, 256, 0, stream>>>(x, w1q, b1, w2frag, b2, pooled);
    fc_kernel<<<256, 512, 0, stream>>>(pooled, fc1wq, fb1, fc2wq, fb2, out);
}